// Round 1
// baseline (137.769 us; speedup 1.0000x reference)
//
#include <hip/hip_runtime.h>

namespace {
constexpr int kB = 8;
constexpr int kN = 4096;
constexpr int kR = 20;
constexpr int kTile = 256;
constexpr int kNT = kN / kTile;                 // 16
constexpr int kTilePairs = kNT * (kNT + 1) / 2; // 136
constexpr float kEps = 1e-8f;
}

// Stage trajectory as float4 (x,y,z,|p|^2) so the inner loop can use uniform
// 16B loads; |p|^2 computed with the reference's rounding order (no fma
// contraction).
__global__ __launch_bounds__(256) void prep_kernel(const float* __restrict__ traj,
                                                   float4* __restrict__ pts) {
  int idx = blockIdx.x * 256 + threadIdx.x;
  if (idx >= kB * kN) return;
  float x = traj[3 * idx + 0];
  float y = traj[3 * idx + 1];
  float z = traj[3 * idx + 2];
  float sq;
  {
#pragma clang fp contract(off)
    sq = ((x * x) + (y * y)) + (z * z);
  }
  pts[idx] = make_float4(x, y, z, sq);
}

// Exact reference arithmetic: d2 = (|i|^2 + |j|^2) - 2*(i.j), each op
// individually rounded (contract off), clamped at EPS.
__device__ __forceinline__ float dist2c(const float4 a, const float4 b) {
#pragma clang fp contract(off)
  float dot = ((a.x * b.x) + (a.y * b.y)) + (a.z * b.z);
  float t = 2.0f * dot;
  float d2 = (a.w + b.w) - t;
  return fmaxf(d2, kEps);
}

__global__ __launch_bounds__(256) void count_kernel(const float4* __restrict__ pts,
                                                    const float* __restrict__ radii,
                                                    unsigned int* __restrict__ counts) {
  const int bid = blockIdx.x;
  const int b = bid / kTilePairs;
  int p = bid % kTilePairs;
  int ti = 0;
  while (p >= kNT - ti) { p -= kNT - ti; ++ti; }
  const int tj = ti + p;

  const float4* __restrict__ base = pts + (size_t)b * kN;
  const int tid = threadIdx.x;
  const float4 pi = base[ti * kTile + tid];

  float r2[kR];
#pragma unroll
  for (int r = 0; r < kR; ++r) {
    float rr = radii[r];
    r2[r] = rr * rr;
  }

  unsigned int cnt[kR];
#pragma unroll
  for (int r = 0; r < kR; ++r) cnt[r] = 0u;

  const float4* __restrict__ jb = base + tj * kTile;

  if (ti != tj) {
#pragma unroll 2
    for (int j = 0; j < kTile; ++j) {
      const float4 pj = jb[j];  // wave-uniform -> scalar load
      const float d2c = dist2c(pi, pj);
#pragma unroll
      for (int r = 0; r < kR; ++r) cnt[r] += (d2c < r2[r]) ? 1u : 0u;
    }
  } else {
    // Diagonal tile: only count j > i (i.e. lds index j > tid).
#pragma unroll 2
    for (int j = 0; j < kTile; ++j) {
      const float4 pj = jb[j];
      float d2c = dist2c(pi, pj);
      d2c = (j > tid) ? d2c : 1e30f;  // masked pairs fail every compare
#pragma unroll
      for (int r = 0; r < kR; ++r) cnt[r] += (d2c < r2[r]) ? 1u : 0u;
    }
  }

  // Block reduction: wave shuffle-reduce, 4 LDS atomics, 1 global atomic per r.
  __shared__ unsigned int hist[kR];
  if (tid < kR) hist[tid] = 0u;
  __syncthreads();
#pragma unroll
  for (int r = 0; r < kR; ++r) {
    unsigned int v = cnt[r];
#pragma unroll
    for (int off = 32; off > 0; off >>= 1) v += __shfl_down(v, off);
    if ((tid & 63) == 0) atomicAdd(&hist[r], v);
  }
  __syncthreads();
  if (tid < kR) atomicAdd(&counts[b * kR + tid], hist[tid]);
}

__global__ void finalize_kernel(const unsigned int* __restrict__ counts,
                                const float* __restrict__ radii,
                                float* __restrict__ out) {
  int b = threadIdx.x;
  if (b >= kB) return;
  const float total = (float)(kN * (kN - 1));  // 16,773,120 < 2^24, exact
  float logC[kR], logr[kR];
#pragma unroll
  for (int r = 0; r < kR; ++r) {
    float c = 2.0f * (float)counts[b * kR + r];  // unordered pairs -> ordered
    logC[r] = logf(c / total + kEps);
    logr[r] = logf(radii[r] + kEps);
  }
  float s = 0.0f;
#pragma unroll
  for (int r = 0; r + 1 < kR; ++r) {
    s += (logC[r + 1] - logC[r]) / (logr[r + 1] - logr[r]);
  }
  s /= (float)(kR - 1);
  out[b] = fminf(fmaxf(s, 0.1f), 3.0f);
}

extern "C" void kernel_launch(void* const* d_in, const int* in_sizes, int n_in,
                              void* d_out, int out_size, void* d_ws, size_t ws_size,
                              hipStream_t stream) {
  const float* traj = (const float*)d_in[0];
  const float* radii = (const float*)d_in[1];
  float* out = (float*)d_out;

  float4* pts = (float4*)d_ws;
  unsigned int* counts =
      (unsigned int*)((char*)d_ws + (size_t)kB * kN * sizeof(float4));

  hipMemsetAsync(counts, 0, kB * kR * sizeof(unsigned int), stream);
  prep_kernel<<<(kB * kN + 255) / 256, 256, 0, stream>>>(traj, pts);
  count_kernel<<<kB * kTilePairs, 256, 0, stream>>>(pts, radii, counts);
  finalize_kernel<<<1, 64, 0, stream>>>(counts, radii, out);
}

// Round 2
// 83.590 us; speedup vs baseline: 1.6481x; 1.6481x over previous
//
#include <hip/hip_runtime.h>

namespace {
constexpr int kB = 8;
constexpr int kN = 4096;
constexpr int kR = 20;
constexpr int kRLo = 10;                          // bins 0..9 are "cold"
constexpr int kTile = 256;                        // i-tile (= block threads)
constexpr int kJC = 128;                          // j-chunk per block
constexpr int kJSplit = kTile / kJC;              // 2
constexpr int kNT = kN / kTile;                   // 16
constexpr int kTilePairs = kNT * (kNT + 1) / 2;   // 136
constexpr int kBlocksPerB = kTilePairs * kJSplit; // 272
constexpr float kEps = 1e-8f;
}

// Stage trajectory as float4 (x,y,z,|p|^2); |p|^2 in the reference's rounding
// order (no fma contraction).
__global__ __launch_bounds__(256) void prep_kernel(const float* __restrict__ traj,
                                                   float4* __restrict__ pts) {
  int idx = blockIdx.x * 256 + threadIdx.x;
  if (idx >= kB * kN) return;
  float x = traj[3 * idx + 0];
  float y = traj[3 * idx + 1];
  float z = traj[3 * idx + 2];
  float sq;
  {
#pragma clang fp contract(off)
    sq = ((x * x) + (y * y)) + (z * z);
  }
  pts[idx] = make_float4(x, y, z, sq);
}

// Exact reference arithmetic: d2 = (|i|^2 + |j|^2) - 2*(i.j), each op
// individually rounded (contract off), clamped at EPS.
__device__ __forceinline__ float dist2c(const float4 a, const float4 b) {
#pragma clang fp contract(off)
  float dot = ((a.x * b.x) + (a.y * b.y)) + (a.z * b.z);
  float t = 2.0f * dot;
  float d2 = (a.w + b.w) - t;
  return fmaxf(d2, kEps);
}

__global__ __launch_bounds__(256) void count_kernel(const float4* __restrict__ pts,
                                                    const float* __restrict__ radii,
                                                    unsigned int* __restrict__ counts) {
  const int bid = blockIdx.x;
  const int b = bid / kBlocksPerB;
  int rem = bid % kBlocksPerB;
  const int jc = rem & (kJSplit - 1);
  int p = rem / kJSplit;
  int ti = 0;
  while (p >= kNT - ti) { p -= kNT - ti; ++ti; }
  const int tj = ti + p;

  const float4* __restrict__ base = pts + (size_t)b * kN;
  const int tid = threadIdx.x;
  const float4 pi = base[ti * kTile + tid];

  float r2[kR];
#pragma unroll
  for (int r = 0; r < kR; ++r) {
    float rr = radii[r];
    r2[r] = rr * rr;  // uniform -> expect SGPR residency
  }
  const float rlo = r2[kRLo - 1];  // guard: any d2 below this -> cold ladder

  unsigned int cnt[kR];
#pragma unroll
  for (int r = 0; r < kR; ++r) cnt[r] = 0u;

  const float4* __restrict__ jb = base + tj * kTile + jc * kJC;

  if (ti != tj) {
#pragma unroll 4
    for (int j = 0; j < kJC; ++j) {
      const float4 pj = jb[j];  // wave-uniform -> scalar load
      const float d2c = dist2c(pi, pj);
#pragma unroll
      for (int r = kRLo; r < kR; ++r) cnt[r] += (d2c < r2[r]) ? 1u : 0u;
      if (__any(d2c < rlo)) {  // ~0.3% of waves
#pragma unroll
        for (int r = 0; r < kRLo; ++r) cnt[r] += (d2c < r2[r]) ? 1u : 0u;
      }
    }
  } else {
    // Diagonal tile: count only global j > global i, i.e. jc*kJC + j > tid.
    const int jbase = jc * kJC;
#pragma unroll 4
    for (int j = 0; j < kJC; ++j) {
      const float4 pj = jb[j];
      float d2c = dist2c(pi, pj);
      d2c = (jbase + j > tid) ? d2c : 1e30f;  // masked pairs fail all compares
#pragma unroll
      for (int r = kRLo; r < kR; ++r) cnt[r] += (d2c < r2[r]) ? 1u : 0u;
      if (__any(d2c < rlo)) {
#pragma unroll
        for (int r = 0; r < kRLo; ++r) cnt[r] += (d2c < r2[r]) ? 1u : 0u;
      }
    }
  }

  // Block reduction: wave shuffle-reduce, LDS atomics, 1 global atomic per r.
  __shared__ unsigned int hist[kR];
  if (tid < kR) hist[tid] = 0u;
  __syncthreads();
#pragma unroll
  for (int r = 0; r < kR; ++r) {
    unsigned int v = cnt[r];
#pragma unroll
    for (int off = 32; off > 0; off >>= 1) v += __shfl_down(v, off);
    if ((tid & 63) == 0) atomicAdd(&hist[r], v);
  }
  __syncthreads();
  if (tid < kR) atomicAdd(&counts[b * kR + tid], hist[tid]);
}

__global__ void finalize_kernel(const unsigned int* __restrict__ counts,
                                const float* __restrict__ radii,
                                float* __restrict__ out) {
  int b = threadIdx.x;
  if (b >= kB) return;
  const float total = (float)(kN * (kN - 1));  // 16,773,120 < 2^24, exact
  float logC[kR], logr[kR];
#pragma unroll
  for (int r = 0; r < kR; ++r) {
    float c = 2.0f * (float)counts[b * kR + r];  // unordered pairs -> ordered
    logC[r] = logf(c / total + kEps);
    logr[r] = logf(radii[r] + kEps);
  }
  float s = 0.0f;
#pragma unroll
  for (int r = 0; r + 1 < kR; ++r) {
    s += (logC[r + 1] - logC[r]) / (logr[r + 1] - logr[r]);
  }
  s /= (float)(kR - 1);
  out[b] = fminf(fmaxf(s, 0.1f), 3.0f);
}

extern "C" void kernel_launch(void* const* d_in, const int* in_sizes, int n_in,
                              void* d_out, int out_size, void* d_ws, size_t ws_size,
                              hipStream_t stream) {
  const float* traj = (const float*)d_in[0];
  const float* radii = (const float*)d_in[1];
  float* out = (float*)d_out;

  float4* pts = (float4*)d_ws;
  unsigned int* counts =
      (unsigned int*)((char*)d_ws + (size_t)kB * kN * sizeof(float4));

  hipMemsetAsync(counts, 0, kB * kR * sizeof(unsigned int), stream);
  prep_kernel<<<(kB * kN + 255) / 256, 256, 0, stream>>>(traj, pts);
  count_kernel<<<kB * kBlocksPerB, 256, 0, stream>>>(pts, radii, counts);
  finalize_kernel<<<1, 64, 0, stream>>>(counts, radii, out);
}

// Round 3
// 79.397 us; speedup vs baseline: 1.7352x; 1.0528x over previous
//
#include <hip/hip_runtime.h>

namespace {
constexpr int kB = 8;
constexpr int kN = 4096;
constexpr int kR = 20;
constexpr int kRLo = 12;                        // bins 0..11 are "cold"
constexpr int kTile = 256;                      // points per tile
constexpr int kNT = kN / kTile;                 // 16
constexpr int kOffPairs = kNT * (kNT - 1) / 2;  // 120 off-diag tile pairs
constexpr int kUnitsPerB = 2 * kOffPairs + kNT; // 240 + 16 = 256 equal units
constexpr float kEps = 1e-8f;
}

// Stage trajectory as float4 (x,y,z,|p|^2); |p|^2 in the reference's rounding
// order (no fma contraction).
__global__ __launch_bounds__(256) void prep_kernel(const float* __restrict__ traj,
                                                   float4* __restrict__ pts) {
  int idx = blockIdx.x * 256 + threadIdx.x;
  if (idx >= kB * kN) return;
  float x = traj[3 * idx + 0];
  float y = traj[3 * idx + 1];
  float z = traj[3 * idx + 2];
  float sq;
  {
#pragma clang fp contract(off)
    sq = ((x * x) + (y * y)) + (z * z);
  }
  pts[idx] = make_float4(x, y, z, sq);
}

// Exact reference arithmetic: d2 = (|i|^2 + |j|^2) - 2*(i.j), each op
// individually rounded (contract off), clamped at EPS. Must stay bit-exact:
// bin-0 membership rides on the reference's cancellation noise.
__device__ __forceinline__ float dist2c(const float4 a, const float4 b) {
#pragma clang fp contract(off)
  float dot = ((a.x * b.x) + (a.y * b.y)) + (a.z * b.z);
  float t = 2.0f * dot;
  float d2 = (a.w + b.w) - t;
  return fmaxf(d2, kEps);
}

__device__ __forceinline__ void ladder(float d2c, const float* r2, float rlo,
                                       unsigned int* cnt) {
#pragma unroll
  for (int r = kRLo; r < kR; ++r) cnt[r] += (d2c < r2[r]) ? 1u : 0u;
  if (__any(d2c < rlo)) {  // ~5% of wave-iters
#pragma unroll
    for (int r = 0; r < kRLo; ++r) cnt[r] += (d2c < r2[r]) ? 1u : 0u;
  }
}

// 2048 blocks, each an equal unit of 256 threads x 128 pair-iterations.
// Off-diag units: half a (ti,tj) tile pair. Diag units: round-robin
// tournament within one tile (127 full rounds + 1 half round) -> zero waste.
__global__ __launch_bounds__(256, 8) void count_kernel(const float4* __restrict__ pts,
                                                       const float* __restrict__ radii,
                                                       unsigned int* __restrict__ counts) {
  const int bid = blockIdx.x;
  const int b = bid / kUnitsPerB;
  const int u = bid % kUnitsPerB;
  const int tid = threadIdx.x;
  const float4* __restrict__ base = pts + (size_t)b * kN;

  __shared__ float4 jtile[kTile];
  __shared__ unsigned int hist[kR];

  int ti, tj, jc, diag;
  if (u < 2 * kOffPairs) {
    int p = u >> 1;
    jc = u & 1;
    diag = 0;
    int t = 0, n = kNT - 1;
    while (p >= n) { p -= n; --n; ++t; }  // decode upper-tri pair index
    ti = t;
    tj = t + 1 + p;
  } else {
    ti = tj = u - 2 * kOffPairs;
    jc = 0;
    diag = 1;
  }

  // Stage the j-points this block needs.
  if (diag) {
    jtile[tid] = base[tj * kTile + tid];              // all 256
  } else if (tid < 128) {
    jtile[tid] = base[tj * kTile + jc * 128 + tid];   // this block's half
  }
  if (tid < kR) hist[tid] = 0u;

  const float4 pi = base[ti * kTile + tid];

  float r2[kR];
#pragma unroll
  for (int r = 0; r < kR; ++r) {
    float rr = radii[r];   // uniform -> scalar loads
    r2[r] = rr * rr;
  }
  const float rlo = r2[kRLo - 1];

  unsigned int cnt[kR];
#pragma unroll
  for (int r = 0; r < kR; ++r) cnt[r] = 0u;

  __syncthreads();

  if (!diag) {
#pragma unroll 4
    for (int k = 0; k < 128; ++k) {
      const float4 pj = jtile[k];  // uniform addr -> LDS broadcast
      ladder(dist2c(pi, pj), r2, rlo, cnt);
    }
  } else {
    // Rounds 1..127: lane t pairs with (t+k) mod 256 -> every unordered pair
    // with separation 1..127 exactly once, all lanes useful.
#pragma unroll 4
    for (int k = 1; k < 128; ++k) {
      const float4 pj = jtile[(tid + k) & (kTile - 1)];
      ladder(dist2c(pi, pj), r2, rlo, cnt);
    }
    // Round 128: separation-128 pairs appear from both ends; keep t<128 only.
    {
      const float4 pj = jtile[(tid + 128) & (kTile - 1)];
      float d2c = dist2c(pi, pj);
      d2c = (tid < 128) ? d2c : 1e30f;  // masked lanes fail every compare
      ladder(d2c, r2, rlo, cnt);
    }
  }

  // Block reduction: wave shuffle-reduce, LDS atomics, 1 global atomic per r.
#pragma unroll
  for (int r = 0; r < kR; ++r) {
    unsigned int v = cnt[r];
#pragma unroll
    for (int off = 32; off > 0; off >>= 1) v += __shfl_down(v, off);
    if ((tid & 63) == 0) atomicAdd(&hist[r], v);
  }
  __syncthreads();
  if (tid < kR) atomicAdd(&counts[b * kR + tid], hist[tid]);
}

__global__ void finalize_kernel(const unsigned int* __restrict__ counts,
                                const float* __restrict__ radii,
                                float* __restrict__ out) {
  int b = threadIdx.x;
  if (b >= kB) return;
  const float total = (float)(kN * (kN - 1));  // 16,773,120 < 2^24, exact
  float logC[kR], logr[kR];
#pragma unroll
  for (int r = 0; r < kR; ++r) {
    float c = 2.0f * (float)counts[b * kR + r];  // unordered pairs -> ordered
    logC[r] = logf(c / total + kEps);
    logr[r] = logf(radii[r] + kEps);
  }
  float s = 0.0f;
#pragma unroll
  for (int r = 0; r + 1 < kR; ++r) {
    s += (logC[r + 1] - logC[r]) / (logr[r + 1] - logr[r]);
  }
  s /= (float)(kR - 1);
  out[b] = fminf(fmaxf(s, 0.1f), 3.0f);
}

extern "C" void kernel_launch(void* const* d_in, const int* in_sizes, int n_in,
                              void* d_out, int out_size, void* d_ws, size_t ws_size,
                              hipStream_t stream) {
  const float* traj = (const float*)d_in[0];
  const float* radii = (const float*)d_in[1];
  float* out = (float*)d_out;

  float4* pts = (float4*)d_ws;
  unsigned int* counts =
      (unsigned int*)((char*)d_ws + (size_t)kB * kN * sizeof(float4));

  hipMemsetAsync(counts, 0, kB * kR * sizeof(unsigned int), stream);
  prep_kernel<<<(kB * kN + 255) / 256, 256, 0, stream>>>(traj, pts);
  count_kernel<<<kB * kUnitsPerB, 256, 0, stream>>>(pts, radii, counts);
  finalize_kernel<<<1, 64, 0, stream>>>(counts, radii, out);
}

// Round 4
// 74.112 us; speedup vs baseline: 1.8589x; 1.0713x over previous
//
#include <hip/hip_runtime.h>

namespace {
constexpr int kB = 8;
constexpr int kN = 4096;
constexpr int kR = 20;
constexpr int kRLo = 10;                        // bins 0..9 cold (ballot path)
constexpr int kHot = kR - kRLo;                 // 10 hot bins, SGPR thresholds
constexpr int kTile = 256;                      // points per tile
constexpr int kNT = kN / kTile;                 // 16
constexpr int kOffPairs = kNT * (kNT - 1) / 2;  // 120
constexpr int kUnitsPerB = 2 * kOffPairs + kNT; // 256 equal units per batch
constexpr int kGroup = 8;                       // iters per branch-free group
constexpr float kEps = 1e-8f;
}

// Stage trajectory as float4 (x,y,z,|p|^2) and the r^2 table; reference
// rounding order (no fma contraction).
__global__ __launch_bounds__(256) void prep_kernel(const float* __restrict__ traj,
                                                   const float* __restrict__ radii,
                                                   float4* __restrict__ pts,
                                                   float* __restrict__ r2t) {
  int idx = blockIdx.x * 256 + threadIdx.x;
  if (blockIdx.x == 0 && threadIdx.x < kR) {
    float rr = radii[threadIdx.x];
    r2t[threadIdx.x] = rr * rr;
  }
  if (idx >= kB * kN) return;
  float x = traj[3 * idx + 0];
  float y = traj[3 * idx + 1];
  float z = traj[3 * idx + 2];
  float sq;
  {
#pragma clang fp contract(off)
    sq = ((x * x) + (y * y)) + (z * z);
  }
  pts[idx] = make_float4(x, y, z, sq);
}

// Exact reference arithmetic: d2 = (|i|^2 + |j|^2) - 2*(i.j), each op
// individually rounded (contract off), clamped at EPS. Bit-exactness matters:
// bin-0 membership rides on the reference's cancellation noise.
__device__ __forceinline__ float dist2c(const float4 a, const float4 b) {
#pragma clang fp contract(off)
  float dot = ((a.x * b.x) + (a.y * b.y)) + (a.z * b.z);
  float t = 2.0f * dot;
  float d2 = (a.w + b.w) - t;
  return fmaxf(d2, kEps);
}

// Rare path: exact counts for cold bins 0..9 via ballot+popcount into LDS.
__device__ __forceinline__ void cold_group(const float* d2s, float rlo,
                                           const float* __restrict__ r2t,
                                           unsigned int* hist, int tid) {
#pragma unroll
  for (int q = 0; q < kGroup; ++q) {
    if (__any(d2s[q] < rlo)) {
#pragma unroll
      for (int r = 0; r < kRLo; ++r) {
        unsigned long long m = __ballot(d2s[q] < r2t[r]);
        if ((tid & 63) == 0 && m)
          atomicAdd(&hist[r], (unsigned int)__popcll(m));
      }
    }
  }
}

// 2048 blocks = 8/CU, each an equal unit: 256 threads x 128 pair-iterations.
// Off-diag units: half a tile pair, j-loads wave-uniform -> scalar SMEM.
// Diag units: round-robin tournament, rotated coalesced loads. Zero waste.
__global__ __launch_bounds__(256, 8) void count_kernel(const float4* __restrict__ pts,
                                                       const float* __restrict__ r2t,
                                                       unsigned int* __restrict__ counts) {
  const int bid = blockIdx.x;
  const int b = bid / kUnitsPerB;
  const int u = bid % kUnitsPerB;
  const int tid = threadIdx.x;
  const float4* __restrict__ base = pts + (size_t)b * kN;

  __shared__ unsigned int hist[kR];
  for (int h = tid; h < kR; h += 256) hist[h] = 0u;

  int ti, tj, jc, diag;
  if (u < 2 * kOffPairs) {
    int p = u >> 1;
    jc = u & 1;
    diag = 0;
    int t = 0, n = kNT - 1;
    while (p >= n) { p -= n; --n; ++t; }  // decode upper-tri pair index
    ti = t;
    tj = t + 1 + p;
  } else {
    ti = tj = u - 2 * kOffPairs;
    jc = 0;
    diag = 1;
  }

  const float4 pi = base[ti * kTile + tid];

  // Hot thresholds r2[10..19]: uniform loads -> SGPR-resident.
  float r2h[kHot];
#pragma unroll
  for (int h = 0; h < kHot; ++h) r2h[h] = r2t[kRLo + h];
  const float rlo = r2t[kRLo - 1];

  unsigned int cnt[kHot];
#pragma unroll
  for (int h = 0; h < kHot; ++h) cnt[h] = 0u;

  __syncthreads();  // hist zeroed before any cold-path atomics

  if (!diag) {
    const float4* __restrict__ jb = base + tj * kTile + jc * 128;
    for (int g = 0; g < 128 / kGroup; ++g) {
      float d2s[kGroup];
      float gmin = 1e30f;
#pragma unroll
      for (int q = 0; q < kGroup; ++q) {
        const float4 pj = jb[g * kGroup + q];  // uniform -> s_load
        float d = dist2c(pi, pj);
        d2s[q] = d;
        gmin = fminf(gmin, d);
#pragma unroll
        for (int h = 0; h < kHot; ++h) cnt[h] += (d < r2h[h]) ? 1u : 0u;
      }
      if (__builtin_expect(__any(gmin < rlo), 0))
        cold_group(d2s, rlo, r2t, hist, tid);
    }
  } else {
    // Tournament: k=1..127 pairs each unordered pair of separation 1..127
    // exactly once; k=128 counts separation-128 pairs from the tid<128 end.
    const float4* __restrict__ tb = base + ti * kTile;
    for (int g = 0; g < 128 / kGroup; ++g) {
      float d2s[kGroup];
      float gmin = 1e30f;
#pragma unroll
      for (int q = 0; q < kGroup; ++q) {
        const int k = g * kGroup + q + 1;  // 1..128, compile-time within body
        const float4 pj = tb[(tid + k) & (kTile - 1)];
        float d = dist2c(pi, pj);
        if (k == 128) d = (tid < 128) ? d : 1e30f;  // mask fails all compares
        d2s[q] = d;
        gmin = fminf(gmin, d);
#pragma unroll
        for (int h = 0; h < kHot; ++h) cnt[h] += (d < r2h[h]) ? 1u : 0u;
      }
      if (__builtin_expect(__any(gmin < rlo), 0))
        cold_group(d2s, rlo, r2t, hist, tid);
    }
  }

  // Hot bins: wave shuffle-reduce, one LDS atomic per wave per bin.
#pragma unroll
  for (int h = 0; h < kHot; ++h) {
    unsigned int v = cnt[h];
#pragma unroll
    for (int off = 32; off > 0; off >>= 1) v += __shfl_down(v, off);
    if ((tid & 63) == 0) atomicAdd(&hist[kRLo + h], v);
  }
  __syncthreads();
  if (tid < kR) atomicAdd(&counts[b * kR + tid], hist[tid]);
}

__global__ void finalize_kernel(const unsigned int* __restrict__ counts,
                                const float* __restrict__ radii,
                                float* __restrict__ out) {
  int b = threadIdx.x;
  if (b >= kB) return;
  const float total = (float)(kN * (kN - 1));  // 16,773,120 < 2^24, exact
  float logC[kR], logr[kR];
#pragma unroll
  for (int r = 0; r < kR; ++r) {
    float c = 2.0f * (float)counts[b * kR + r];  // unordered pairs -> ordered
    logC[r] = logf(c / total + kEps);
    logr[r] = logf(radii[r] + kEps);
  }
  float s = 0.0f;
#pragma unroll
  for (int r = 0; r + 1 < kR; ++r) {
    s += (logC[r + 1] - logC[r]) / (logr[r + 1] - logr[r]);
  }
  s /= (float)(kR - 1);
  out[b] = fminf(fmaxf(s, 0.1f), 3.0f);
}

extern "C" void kernel_launch(void* const* d_in, const int* in_sizes, int n_in,
                              void* d_out, int out_size, void* d_ws, size_t ws_size,
                              hipStream_t stream) {
  const float* traj = (const float*)d_in[0];
  const float* radii = (const float*)d_in[1];
  float* out = (float*)d_out;

  float4* pts = (float4*)d_ws;
  unsigned int* counts =
      (unsigned int*)((char*)d_ws + (size_t)kB * kN * sizeof(float4));
  float* r2t = (float*)((char*)d_ws + (size_t)kB * kN * sizeof(float4) +
                        kB * kR * sizeof(unsigned int));

  hipMemsetAsync(counts, 0, kB * kR * sizeof(unsigned int), stream);
  prep_kernel<<<(kB * kN + 255) / 256, 256, 0, stream>>>(traj, radii, pts, r2t);
  count_kernel<<<kB * kUnitsPerB, 256, 0, stream>>>(pts, r2t, counts);
  finalize_kernel<<<1, 64, 0, stream>>>(counts, radii, out);
}